// Round 1
// baseline (4291.999 us; speedup 1.0000x reference)
//
#include <hip/hip_runtime.h>
#include <hip/hip_bf16.h>
#include <math.h>

#define DEVI __device__ __forceinline__

typedef __attribute__((ext_vector_type(8))) short bf16x8;
typedef __attribute__((ext_vector_type(4))) float f32x4;

#define MFMA(a, b, c) __builtin_amdgcn_mfma_f32_16x16x32_bf16((a), (b), (c), 0, 0, 0)

DEVI short f2bf(float f) {
    unsigned u = __builtin_bit_cast(unsigned, f);
    unsigned r = (u + 0x7FFFu + ((u >> 16) & 1u)) >> 16;
    return (short)r;
}
DEVI float bf2f(short s) {
    unsigned u = ((unsigned)(unsigned short)s) << 16;
    return __builtin_bit_cast(float, u);
}
// Byte offset into a row-major LDS tile with XOR bank swizzle (rows are
// multiples of 128B -> unswizzled column reads would be 16/32-way conflicts).
DEVI int swz(int row, int cb, int ld) {
    return row * ld + (cb ^ ((row & 7) << 4));
}
// Load 8 consecutive fp32 from global, round-to-nearest-even to bf16 fragment.
DEVI bf16x8 gload_bf8(const float* p) {
    const f32x4* q = (const f32x4*)p;
    f32x4 a = q[0], b = q[1];
    bf16x8 r;
    r[0] = f2bf(a[0]); r[1] = f2bf(a[1]); r[2] = f2bf(a[2]); r[3] = f2bf(a[3]);
    r[4] = f2bf(b[0]); r[5] = f2bf(b[1]); r[6] = f2bf(b[2]); r[7] = f2bf(b[3]);
    return r;
}

// LDS layout (dynamic, 120576 B):
//  SW  @      0 : 49x256 bf16 (512B rows, swz)  : normed win;   later y = LN2 out
//  Q   @  25088 : 49x256 bf16                   : q;  later sO; later sH (MLP chunk)
//  R2  @  50176 : 49x256 bf16 k;  stage0 sX[256][52] f32;  later sW2[49][261] f32
//  VT  @  75264 : 256x64  bf16 (128B rows, swz) : v transposed [d][m]
//  SATT@ 108032 : 2 x (49x64 bf16, 128B rows)   : per-wave-group attention tile
__global__ __launch_bounds__(512, 1) void swin_kernel(
    const float* __restrict__ x,
    const float* __restrict__ n1w, const float* __restrict__ n1b,
    const float* __restrict__ Wq,  const float* __restrict__ Bq,
    const float* __restrict__ Wo,  const float* __restrict__ Bo,
    const float* __restrict__ n2w, const float* __restrict__ n2b,
    const float* __restrict__ W1,  const float* __restrict__ B1,
    const float* __restrict__ W2,  const float* __restrict__ B2,
    float* __restrict__ out)
{
    extern __shared__ __align__(16) char smem[];
    constexpr int SW = 0, Q = 25088, R2 = 50176, VT = 75264, SATT = 108032;

    const int bid = blockIdx.x;
    const int b  = bid >> 10;
    const int wh = (bid >> 5) & 31;
    const int w7 = bid & 31;
    const int tid = threadIdx.x;
    const int wv = tid >> 6, lane = tid & 63, lg = lane >> 4, l15 = lane & 15;
    const f32x4 fzero = {0.f, 0.f, 0.f, 0.f};

    // ---------------- stage 0: gather window into sX[c][l] ----------------
    {
        float* sX = (float*)(smem + R2);
        const float* xb = x + (size_t)b * (256 * 224 * 224);
        for (int i = tid; i < 256 * 49; i += 512) {
            int c = i / 49, l = i - c * 49;
            int hh = wh * 7 + l / 7, ww = w7 * 7 + (l % 7);
            sX[c * 52 + l] = xb[((size_t)c * 224 + hh) * 224 + ww];
        }
    }
    __syncthreads();
    // ---------------- LN1 -> sW (bf16, swizzled) ----------------
    {
        const int l = tid >> 3, s = tid & 7;
        if (l < 49) {
            const float* sX = (const float*)(smem + R2);
            float sum = 0.f, sq = 0.f;
            for (int ii = 0; ii < 32; ++ii) {
                int c = s * 32 + ((ii + tid) & 31);
                float v = sX[c * 52 + l];
                sum += v; sq += v * v;
            }
#pragma unroll
            for (int m = 1; m < 8; m <<= 1) { sum += __shfl_xor(sum, m); sq += __shfl_xor(sq, m); }
            float mean = sum * (1.f / 256.f);
            float rstd = rsqrtf(sq * (1.f / 256.f) - mean * mean + 1e-5f);
            for (int ii = 0; ii < 32; ++ii) {
                int c = s * 32 + ii;
                float v = (sX[c * 52 + l] - mean) * rstd * n1w[c] + n1b[c];
                *(short*)(smem + SW + swz(l, c * 2, 512)) = f2bf(v);
            }
        }
    }
    __syncthreads();
    // ---------------- QKV: qkv = sW @ Wq^T + Bq  (wave -> 96 cols) --------
    for (int ct = 0; ct < 6; ++ct) {
        const int j = (wv * 6 + ct) * 16 + l15;          // 0..767
        f32x4 a0 = fzero, a1 = fzero, a2 = fzero, a3 = fzero;
        const float* wr = Wq + (size_t)j * 256 + lg * 8;
#pragma unroll
        for (int kk = 0; kk < 8; ++kk) {
            bf16x8 bf = gload_bf8(wr + kk * 32);
            const int cb = kk * 64 + lg * 16;
            bf16x8 f0 = *(const bf16x8*)(smem + SW + swz(l15,      cb, 512));
            bf16x8 f1 = *(const bf16x8*)(smem + SW + swz(16 + l15, cb, 512));
            bf16x8 f2 = *(const bf16x8*)(smem + SW + swz(32 + l15, cb, 512));
            bf16x8 f3 = *(const bf16x8*)(smem + SW + swz(48,       cb, 512)); // M-pad clamp
            a0 = MFMA(f0, bf, a0);
            a1 = MFMA(f1, bf, a1);
            a2 = MFMA(f2, bf, a2);
            a3 = MFMA(f3, bf, a3);
        }
        const float bias = Bq[j];
#pragma unroll
        for (int mt = 0; mt < 4; ++mt) {
            f32x4 av = (mt == 0) ? a0 : (mt == 1) ? a1 : (mt == 2) ? a2 : a3;
#pragma unroll
            for (int r = 0; r < 4; ++r) {
                const int row = mt * 16 + lg * 4 + r;
                const short hv = f2bf(av[r] + bias);
                if (j < 256) {
                    if (row < 49) *(short*)(smem + Q + swz(row, j * 2, 512)) = hv;
                } else if (j < 512) {
                    if (row < 49) *(short*)(smem + R2 + swz(row, (j - 256) * 2, 512)) = hv;
                } else {
                    // v stored transposed: v_t[d][m], m up to 63 (pad rows finite)
                    *(short*)(smem + VT + swz(j - 512, row * 2, 128)) = hv;
                }
            }
        }
    }
    __syncthreads();
    // ---------------- attention: 2 wave-groups x 4 row-strips -------------
    const int grp = wv >> 2;         // head parity group
    const int mts = wv & 3;          // 16-row strip
    int arow = mts * 16 + l15; if (arow > 48) arow = 48;
    char* satt = smem + SATT + grp * 6272;
    f32x4 oacc[8];
#pragma unroll
    for (int i = 0; i < 8; ++i) oacc[i] = fzero;
#pragma unroll
    for (int it = 0; it < 4; ++it) {
        const int h = it * 2 + grp;
        const int hb = h * 64 + lg * 16;   // byte offset of this head's k-slice
        bf16x8 qa = *(const bf16x8*)(smem + Q + swz(arow, hb, 512));
        f32x4 s0 = fzero, s1 = fzero, s2 = fzero, s3 = fzero;
        {
            bf16x8 k0 = *(const bf16x8*)(smem + R2 + swz(l15,      hb, 512));
            bf16x8 k1 = *(const bf16x8*)(smem + R2 + swz(16 + l15, hb, 512));
            bf16x8 k2 = *(const bf16x8*)(smem + R2 + swz(32 + l15, hb, 512));
            bf16x8 k3 = *(const bf16x8*)(smem + R2 + swz(48,       hb, 512));
            s0 = MFMA(qa, k0, s0);
            s1 = MFMA(qa, k1, s1);
            s2 = MFMA(qa, k2, s2);
            s3 = MFMA(qa, k3, s3);
        }
        const float scale = 0.17677669529663687f; // 1/sqrt(32)
#pragma unroll
        for (int rj = 0; rj < 4; ++rj) {
            float v0 = s0[rj] * scale, v1 = s1[rj] * scale;
            float v2 = s2[rj] * scale, v3 = s3[rj] * scale;
            const int c1 = 16 + l15, c2 = 32 + l15, c3 = 48 + l15;
            float mx = fmaxf(fmaxf(v0, v1), v2);
            if (c3 < 49) mx = fmaxf(mx, v3);
#pragma unroll
            for (int mm = 1; mm < 16; mm <<= 1) mx = fmaxf(mx, __shfl_xor(mx, mm));
            float e0 = __expf(v0 - mx);
            float e1 = __expf(v1 - mx);
            float e2 = __expf(v2 - mx);
            float e3 = (c3 < 49) ? __expf(v3 - mx) : 0.f;
            float sm = e0 + e1 + e2 + e3;
#pragma unroll
            for (int mm = 1; mm < 16; mm <<= 1) sm += __shfl_xor(sm, mm);
            const float inv = 1.f / sm;
            const int row = mts * 16 + lg * 4 + rj;
            if (row < 49) {
                *(short*)(satt + swz(row, l15 * 2, 128)) = f2bf(e0 * inv);
                *(short*)(satt + swz(row, c1 * 2, 128)) = f2bf(e1 * inv);
                *(short*)(satt + swz(row, c2 * 2, 128)) = f2bf(e2 * inv);
                *(short*)(satt + swz(row, c3 * 2, 128)) = f2bf(e3 * inv);
            }
        }
        __syncthreads();
        // PV: O[strip, h*32..h*32+32) += att @ v
#pragma unroll
        for (int kk = 0; kk < 2; ++kk) {
            const int kb = kk * 64 + lg * 16;
            bf16x8 pa  = *(const bf16x8*)(satt + swz(arow, kb, 128));
            bf16x8 vb0 = *(const bf16x8*)(smem + VT + swz(h * 32 + l15,      kb, 128));
            bf16x8 vb1 = *(const bf16x8*)(smem + VT + swz(h * 32 + 16 + l15, kb, 128));
            oacc[it * 2 + 0] = MFMA(pa, vb0, oacc[it * 2 + 0]);
            oacc[it * 2 + 1] = MFMA(pa, vb1, oacc[it * 2 + 1]);
        }
        __syncthreads();
    }
    // write O (bf16) into Q region (q is dead now)
#pragma unroll
    for (int it = 0; it < 4; ++it) {
        const int h = it * 2 + grp;
#pragma unroll
        for (int nt = 0; nt < 2; ++nt) {
#pragma unroll
            for (int r = 0; r < 4; ++r) {
                const int row = mts * 16 + lg * 4 + r;
                if (row < 49) {
                    const int col = h * 32 + nt * 16 + l15;
                    *(short*)(smem + Q + swz(row, col * 2, 512)) = f2bf(oacc[it * 2 + nt][r]);
                }
            }
        }
    }
    __syncthreads();
    // ---------------- out-proj + residual -> sW2 (fp32 [49][261]) ---------
#pragma unroll
    for (int ct = 0; ct < 2; ++ct) {
        const int j = wv * 32 + ct * 16 + l15;
        f32x4 a0 = fzero, a1 = fzero, a2 = fzero, a3 = fzero;
        const float* wr = Wo + (size_t)j * 256 + lg * 8;
#pragma unroll
        for (int kk = 0; kk < 8; ++kk) {
            bf16x8 bf = gload_bf8(wr + kk * 32);
            const int cb = kk * 64 + lg * 16;
            bf16x8 f0 = *(const bf16x8*)(smem + Q + swz(l15,      cb, 512));
            bf16x8 f1 = *(const bf16x8*)(smem + Q + swz(16 + l15, cb, 512));
            bf16x8 f2 = *(const bf16x8*)(smem + Q + swz(32 + l15, cb, 512));
            bf16x8 f3 = *(const bf16x8*)(smem + Q + swz(48,       cb, 512));
            a0 = MFMA(f0, bf, a0);
            a1 = MFMA(f1, bf, a1);
            a2 = MFMA(f2, bf, a2);
            a3 = MFMA(f3, bf, a3);
        }
        const float bias = Bo[j];
        float* w2p = (float*)(smem + R2);
#pragma unroll
        for (int mt = 0; mt < 4; ++mt) {
            f32x4 av = (mt == 0) ? a0 : (mt == 1) ? a1 : (mt == 2) ? a2 : a3;
#pragma unroll
            for (int r = 0; r < 4; ++r) {
                const int row = mt * 16 + lg * 4 + r;
                if (row < 49) {
                    float wn = bf2f(*(const short*)(smem + SW + swz(row, j * 2, 512)));
                    w2p[row * 261 + j] = wn + av[r] + bias;
                }
            }
        }
    }
    __syncthreads();
    // ---------------- LN2 -> y (bf16, SW region; sW dead) -----------------
    {
        const int l = tid >> 3, s = tid & 7;
        if (l < 49) {
            const float* wp = (const float*)(smem + R2) + l * 261;
            float sum = 0.f, sq = 0.f;
            for (int ii = 0; ii < 32; ++ii) {
                int c = s * 32 + ((ii + tid) & 31);
                float v = wp[c];
                sum += v; sq += v * v;
            }
#pragma unroll
            for (int m = 1; m < 8; m <<= 1) { sum += __shfl_xor(sum, m); sq += __shfl_xor(sq, m); }
            float mean = sum * (1.f / 256.f);
            float rstd = rsqrtf(sq * (1.f / 256.f) - mean * mean + 1e-5f);
            for (int ii = 0; ii < 32; ++ii) {
                int c = s * 32 + ii;
                float v = (wp[c] - mean) * rstd * n2w[c] + n2b[c];
                *(short*)(smem + SW + swz(l, c * 2, 512)) = f2bf(v);
            }
        }
    }
    __syncthreads();
    // ---------------- MLP (4 chunks of 256 hidden) ------------------------
    f32x4 macc[8];
#pragma unroll
    for (int i = 0; i < 8; ++i) macc[i] = fzero;
#pragma unroll 1
    for (int chunk = 0; chunk < 4; ++chunk) {
        // MLP1 + GELU -> sH (Q region; sO dead)
#pragma unroll
        for (int ct = 0; ct < 2; ++ct) {
            const int lcol = wv * 32 + ct * 16 + l15;       // 0..255 within chunk
            const int jj = chunk * 256 + lcol;
            f32x4 a0 = fzero, a1 = fzero, a2 = fzero, a3 = fzero;
            const float* wr = W1 + (size_t)jj * 256 + lg * 8;
#pragma unroll
            for (int kk = 0; kk < 8; ++kk) {
                bf16x8 bf = gload_bf8(wr + kk * 32);
                const int cb = kk * 64 + lg * 16;
                bf16x8 f0 = *(const bf16x8*)(smem + SW + swz(l15,      cb, 512));
                bf16x8 f1 = *(const bf16x8*)(smem + SW + swz(16 + l15, cb, 512));
                bf16x8 f2 = *(const bf16x8*)(smem + SW + swz(32 + l15, cb, 512));
                bf16x8 f3 = *(const bf16x8*)(smem + SW + swz(48,       cb, 512));
                a0 = MFMA(f0, bf, a0);
                a1 = MFMA(f1, bf, a1);
                a2 = MFMA(f2, bf, a2);
                a3 = MFMA(f3, bf, a3);
            }
            const float bias = B1[jj];
#pragma unroll
            for (int mt = 0; mt < 4; ++mt) {
                f32x4 av = (mt == 0) ? a0 : (mt == 1) ? a1 : (mt == 2) ? a2 : a3;
#pragma unroll
                for (int r = 0; r < 4; ++r) {
                    const int row = mt * 16 + lg * 4 + r;
                    if (row < 49) {
                        float v = av[r] + bias;
                        float g = 0.5f * v * (1.f + erff(v * 0.70710678118654752f));
                        *(short*)(smem + Q + swz(row, lcol * 2, 512)) = f2bf(g);
                    }
                }
            }
        }
        __syncthreads();
        // MLP2 partial accumulate
#pragma unroll
        for (int ct = 0; ct < 2; ++ct) {
            const int j = wv * 32 + ct * 16 + l15;
            const float* wr = W2 + (size_t)j * 1024 + chunk * 256 + lg * 8;
#pragma unroll
            for (int kk = 0; kk < 8; ++kk) {
                bf16x8 bf = gload_bf8(wr + kk * 32);
                const int cb = kk * 64 + lg * 16;
                bf16x8 f0 = *(const bf16x8*)(smem + Q + swz(l15,      cb, 512));
                bf16x8 f1 = *(const bf16x8*)(smem + Q + swz(16 + l15, cb, 512));
                bf16x8 f2 = *(const bf16x8*)(smem + Q + swz(32 + l15, cb, 512));
                bf16x8 f3 = *(const bf16x8*)(smem + Q + swz(48,       cb, 512));
                macc[ct * 4 + 0] = MFMA(f0, bf, macc[ct * 4 + 0]);
                macc[ct * 4 + 1] = MFMA(f1, bf, macc[ct * 4 + 1]);
                macc[ct * 4 + 2] = MFMA(f2, bf, macc[ct * 4 + 2]);
                macc[ct * 4 + 3] = MFMA(f3, bf, macc[ct * 4 + 3]);
            }
        }
        __syncthreads();
    }
    // final residual: sW2 += mlp2 + b2
#pragma unroll
    for (int ct = 0; ct < 2; ++ct) {
        const int j = wv * 32 + ct * 16 + l15;
        const float bias = B2[j];
        float* w2p = (float*)(smem + R2);
#pragma unroll
        for (int mt = 0; mt < 4; ++mt) {
#pragma unroll
            for (int r = 0; r < 4; ++r) {
                const int row = mt * 16 + lg * 4 + r;
                if (row < 49) {
                    w2p[row * 261 + j] += macc[ct * 4 + mt][r] + bias;
                }
            }
        }
    }
    __syncthreads();
    // ---------------- window-reverse scatter store ------------------------
    {
        const float* w2p = (const float*)(smem + R2);
        for (int i = tid; i < 256 * 49; i += 512) {
            int c = i / 49, l = i - c * 49;
            int hh = wh * 7 + l / 7, ww = w7 * 7 + (l % 7);
            out[((size_t)(b * 256 + c) * 224 + hh) * 224 + ww] = w2p[l * 261 + c];
        }
    }
}

extern "C" void kernel_launch(void* const* d_in, const int* in_sizes, int n_in,
                              void* d_out, int out_size, void* d_ws, size_t ws_size,
                              hipStream_t stream) {
    const float* x   = (const float*)d_in[0];
    const float* n1w = (const float*)d_in[1];
    const float* n1b = (const float*)d_in[2];
    const float* Wq  = (const float*)d_in[3];
    const float* Bq  = (const float*)d_in[4];
    const float* Wo  = (const float*)d_in[5];
    const float* Bo  = (const float*)d_in[6];
    const float* n2w = (const float*)d_in[7];
    const float* n2b = (const float*)d_in[8];
    const float* W1  = (const float*)d_in[9];
    const float* B1  = (const float*)d_in[10];
    const float* W2  = (const float*)d_in[11];
    const float* B2  = (const float*)d_in[12];
    float* out = (float*)d_out;
    (void)d_ws; (void)ws_size; (void)in_sizes; (void)n_in; (void)out_size;

    dim3 grid(8192), block(512);
    swin_kernel<<<grid, block, 120576, stream>>>(x, n1w, n1b, Wq, Bq, Wo, Bo,
                                                 n2w, n2b, W1, B1, W2, B2, out);
}